// Round 1
// 669.309 us; speedup vs baseline: 1.0139x; 1.0139x over previous
//
#include <hip/hip_runtime.h>
#include <stdint.h>

// ---------------------------------------------------------------------------
// MLP: out = gelu_tanh(x @ w1) @ w2, per-expert (E=8, T=2048, H=1024, F=4096)
// R4: GEMM ported to the 256x256 8-phase counted-vmcnt template
// (T1 XCD swizzle + T2 XOR LDS swizzle + T3/T4 8-phase counted vmcnt +
//  T5 setprio). BK=64, 8 waves (2Mx4N), 128 KiB LDS double-buffer.
// Slab schedule (per iteration = 2 K-tiles, tiles 2i->slot0, 2i+1->slot1):
//   ph1 Q(0,0)s0 reads A0,B0      stages (2i+1).A1 -> s1.A1 (dead prev ph7)
//   ph2 Q(0,1)s0 reads B1         stages (2i+2).A0 -> s0.A0 (dead ph1)
//   ph3 Q(1,0)s0 reads A1         stages (2i+2).B0 -> s0.B0 (dead ph1)
//   ph4 Q(1,1)s0 vmcnt(6)         stages (2i+2).B1 -> s0.B1 (dead ph2)
//   ph5..ph8 same on slot1, stages (2i+2).A1->s0.A1, (2i+3).{A0,B0,B1}->s1
// vmcnt(6) at ph4/ph8 keeps 3 half-slabs (6 loads) in flight across the
// barrier; a slab is only written >=1 barrier after its last ds_read retires.
// ---------------------------------------------------------------------------

typedef __bf16  bf16x8  __attribute__((ext_vector_type(8)));
typedef float   floatx4 __attribute__((ext_vector_type(4)));

__device__ __forceinline__ uint16_t f2bf(float f) {
    uint32_t u = __float_as_uint(f);
    u += 0x7FFF + ((u >> 16) & 1);       // round-to-nearest-even
    return (uint16_t)(u >> 16);
}

__device__ __forceinline__ uint32_t pack2bf(float lo, float hi) {
    return (uint32_t)f2bf(lo) | ((uint32_t)f2bf(hi) << 16);
}

// gelu_tanh(x) == x * sigmoid(2u), u = sqrt(2/pi)*(x + 0.044715 x^3)
__device__ __forceinline__ float gelu_tanh_f(float x) {
    float u2 = 1.5957691216057308f * (x + 0.044715f * x * x * x);
    return x / (1.0f + __expf(-u2));
}

// async global->LDS, 16 bytes per lane; dest = wave-uniform base + lane*16.
__device__ __forceinline__ void async16(const void* g, void* l) {
    __builtin_amdgcn_global_load_lds(
        (__attribute__((address_space(1))) void*)(g),
        (__attribute__((address_space(3))) void*)(l),
        16, 0, 0);
}

#define BARF() do { asm volatile("" ::: "memory");               \
                    __builtin_amdgcn_s_barrier();                \
                    asm volatile("" ::: "memory"); } while (0)

// ---------------------------------------------------------------------------
// fp32 -> bf16 elementwise convert (x), 4 elements/thread
// ---------------------------------------------------------------------------
__global__ void cvt_f32_bf16_x4(const float* __restrict__ in,
                                uint16_t* __restrict__ out, int n4) {
    int i = blockIdx.x * blockDim.x + threadIdx.x;
    if (i >= n4) return;
    float4 v = ((const float4*)in)[i];
    ushort4 o;
    o.x = f2bf(v.x); o.y = f2bf(v.y); o.z = f2bf(v.z); o.w = f2bf(v.w);
    ((ushort4*)out)[i] = o;
}

// ---------------------------------------------------------------------------
// Batched transpose + convert: in [E][R][C] fp32 -> out [E][C][R] bf16.
// ---------------------------------------------------------------------------
__global__ void transpose_cvt(const float* __restrict__ in,
                              uint16_t* __restrict__ out, int R, int C) {
    __shared__ uint32_t lds32[64][33];
    const int e = blockIdx.z;
    in  += (size_t)e * R * C;
    out += (size_t)e * C * R;
    const int c0 = blockIdx.x * 64, r0 = blockIdx.y * 64;
    const int t = threadIdx.x;

    const int g = t >> 4;
    const int col4 = (t & 15) * 4;
    const float* p = in + (size_t)(r0 + 4 * g) * C + c0 + col4;
    float4 v0 = ((const float4*)(p))[0];
    float4 v1 = ((const float4*)(p + C))[0];
    float4 v2 = ((const float4*)(p + 2 * (size_t)C))[0];
    float4 v3 = ((const float4*)(p + 3 * (size_t)C))[0];

    lds32[col4 + 0][2 * g]     = pack2bf(v0.x, v1.x);
    lds32[col4 + 1][2 * g]     = pack2bf(v0.y, v1.y);
    lds32[col4 + 2][2 * g]     = pack2bf(v0.z, v1.z);
    lds32[col4 + 3][2 * g]     = pack2bf(v0.w, v1.w);
    lds32[col4 + 0][2 * g + 1] = pack2bf(v2.x, v3.x);
    lds32[col4 + 1][2 * g + 1] = pack2bf(v2.y, v3.y);
    lds32[col4 + 2][2 * g + 1] = pack2bf(v2.z, v3.z);
    lds32[col4 + 3][2 * g + 1] = pack2bf(v2.w, v3.w);
    __syncthreads();

    const int c = t >> 2, ch = t & 3;
    uint32_t v[8];
#pragma unroll
    for (int k = 0; k < 8; ++k) v[k] = lds32[c][ch * 8 + k];
    uint16_t* op = out + (size_t)(c0 + c) * R + r0 + ch * 16;
    *(uint4*)(op)     = make_uint4(v[0], v[1], v[2], v[3]);
    *(uint4*)(op + 8) = make_uint4(v[4], v[5], v[6], v[7]);
}

// ---------------------------------------------------------------------------
// 8-phase 256x256 GEMM helpers
// ---------------------------------------------------------------------------
template <int QM>
__device__ __forceinline__ void rdA(bf16x8 (&af)[4][2], const uint16_t* src,
                                    int c0, int c1) {
#pragma unroll
    for (int m = 0; m < 4; ++m) {
        af[m][0] = *(const bf16x8*)(src + QM * 8192 + m * 1024 + c0);
        af[m][1] = *(const bf16x8*)(src + QM * 8192 + m * 1024 + c1);
    }
}

template <int QN>
__device__ __forceinline__ void rdB(bf16x8 (&b)[2][2], const uint16_t* src,
                                    int c0, int c1) {
#pragma unroll
    for (int n = 0; n < 2; ++n) {
        b[n][0] = *(const bf16x8*)(src + QN * 8192 + n * 1024 + c0);
        b[n][1] = *(const bf16x8*)(src + QN * 8192 + n * 1024 + c1);
    }
}

template <int QM, int QN>
__device__ __forceinline__ void mm16(floatx4 (&acc)[8][4],
                                     const bf16x8 (&af)[4][2],
                                     const bf16x8 (&b)[2][2]) {
    __builtin_amdgcn_s_setprio(1);
#pragma unroll
    for (int m = 0; m < 4; ++m)
#pragma unroll
        for (int n = 0; n < 2; ++n) {
            floatx4 c = acc[QM * 4 + m][QN * 2 + n];
            c = __builtin_amdgcn_mfma_f32_16x16x32_bf16(af[m][0], b[n][0], c, 0, 0, 0);
            c = __builtin_amdgcn_mfma_f32_16x16x32_bf16(af[m][1], b[n][1], c, 0, 0, 0);
            acc[QM * 4 + m][QN * 2 + n] = c;
        }
    __builtin_amdgcn_s_setprio(0);
}

// ---------------------------------------------------------------------------
// GEMM: C[M][N] = A[M][K] @ Bt[N][K]^T, bf16 in, fp32 accum.
// 256x256 tile, BK=64, 512 threads = 8 waves (2Mx4N), 128x64 per wave.
// LDS per operand-slot: [256][64] elems, physical row p = slab*128+sub,
// chunk pc = kc ^ (p&7) (XOR swizzle, bank-conflict-free b128 reads;
// source-side global address permutation keeps global_load_lds linear dest).
// A slab qm: physical rows qm*128 + wm*64 + r  (logical row wm*128+qm*64+r)
// B slab qn: physical rows qn*128 + wn*32 + r  (logical col wn*64+qn*32+r)
// GELU=true: gelu+bf16 store; else fp32. Batched via flattened grid (XCD swz).
// M,N mult of 256, K mult of 128, grid mult of 8.
// ---------------------------------------------------------------------------
template <bool GELU>
__global__ __launch_bounds__(512, 2)
void gemm_bt_8ph(const uint16_t* __restrict__ A,
                 const uint16_t* __restrict__ Bt,
                 void* __restrict__ Cv, int M, int N, int K) {
    __shared__ __attribute__((aligned(16))) uint16_t lds_a[2][256 * 64];
    __shared__ __attribute__((aligned(16))) uint16_t lds_b[2][256 * 64];

    // T1: bijective XCD-chunked swizzle on the flattened 3D grid
    const int nx = gridDim.x, ny = gridDim.y;
    int flat = blockIdx.x + nx * (blockIdx.y + ny * blockIdx.z);
    const int nwg = nx * ny * (int)gridDim.z;      // multiple of 8 by launch
    flat = (flat & 7) * (nwg >> 3) + (flat >> 3);
    const int bx  = flat % nx;
    const int tmp = flat / nx;
    const int by  = tmp % ny;
    const int e   = tmp / ny;

    A  += (size_t)e * M * K;
    Bt += (size_t)e * N * K;
    const size_t cEbase = (size_t)e * M * N;
    const int rowBase = by * 256, colBase = bx * 256;

    const int tid  = threadIdx.x;
    const int lane = tid & 63, wave = tid >> 6;
    const int wm = wave >> 2, wn = wave & 3;
    const int quad = lane >> 4, l15 = lane & 15, lx = l15 & 7;
    const int c0 = (quad ^ lx) * 8;          // k-chunk offsets (elems), ksub 0
    const int c1 = ((4 + quad) ^ lx) * 8;    // ksub 1

    const size_t K32  = (size_t)32 * K;
    const size_t K64  = (size_t)64 * K;
    const size_t K128 = (size_t)128 * K;

    // staging: thread t covers physical sub-row (t>>3), chunk (t&7);
    // stored logical chunk kc = (t&7) ^ ((t>>3)&7)  -> fold into global addr.
    const int sxor = ((tid & 7) ^ ((tid >> 3) & 7)) * 8;
    const uint16_t* gA = A  + (size_t)(rowBase + (tid >> 3)) * K + sxor;
    const uint16_t* gB = Bt + (size_t)(colBase + (tid >> 8) * 64 +
                                       ((tid >> 3) & 31)) * K + sxor;

    uint16_t* sA0 = lds_a[0] + tid * 8;
    uint16_t* sA1 = lds_a[1] + tid * 8;
    uint16_t* sB0 = lds_b[0] + tid * 8;
    uint16_t* sB1 = lds_b[1] + tid * 8;

    const uint16_t* aRd0 = lds_a[0] + wm * 4096 + l15 * 64;
    const uint16_t* aRd1 = lds_a[1] + wm * 4096 + l15 * 64;
    const uint16_t* bRd0 = lds_b[0] + wn * 2048 + l15 * 64;
    const uint16_t* bRd1 = lds_b[1] + wn * 2048 + l15 * 64;

#define STG_A(dst, qmv, koff) do {                                   \
        const uint16_t* g_ = gA + (qmv) * K64 + (koff);              \
        async16(g_,        (dst) + (qmv) * 8192);                    \
        async16(g_ + K128, (dst) + (qmv) * 8192 + 4096); } while (0)
#define STG_B(dst, qnv, koff) do {                                   \
        const uint16_t* g_ = gB + (qnv) * K32 + (koff);              \
        async16(g_,        (dst) + (qnv) * 8192);                    \
        async16(g_ + K128, (dst) + (qnv) * 8192 + 4096); } while (0)
#define WAITL0() asm volatile("s_waitcnt lgkmcnt(0)" ::: "memory")
#define WAITV6() asm volatile("s_waitcnt vmcnt(6)"  ::: "memory")

    floatx4 acc[8][4] = {};
    bf16x8 af[4][2], bq0[2][2], bq1[2][2];

    const int KT = K >> 6;        // K-tiles of 64
    const int NI = KT >> 1;       // iterations (2 K-tiles each)

    // prologue: tile0 {A0,B0,B1,A1} -> slot0 ; tile1 {A0,B0,B1} -> slot1
    STG_A(sA0, 0, 0); STG_B(sB0, 0, 0); STG_B(sB0, 1, 0); STG_A(sA0, 1, 0);
    STG_A(sA1, 0, 64); STG_B(sB1, 0, 64); STG_B(sB1, 1, 64);
    WAITV6();                     // tile0's 8 loads landed; tile1's 6 in flight
    BARF();

#pragma unroll 1
    for (int i = 0; i < NI; ++i) {
        const size_t oB = (size_t)(2 * i + 1) * 64;              // tile 2i+1
        const int t2 = (2 * i + 2 < KT) ? (2 * i + 2) : 0;       // wrap: dead-slab garbage
        const size_t o2 = (size_t)t2 * 64;
        const size_t o3 = o2 + 64;

        // ph1: Q(0,0) slot0 ; stage (2i+1).A1 -> slot1
        rdA<0>(af, aRd0, c0, c1); rdB<0>(bq0, bRd0, c0, c1);
        STG_A(sA1, 1, oB);
        BARF(); WAITL0();
        mm16<0, 0>(acc, af, bq0);
        BARF();

        // ph2: Q(0,1) slot0 ; stage (2i+2).A0 -> slot0
        rdB<1>(bq1, bRd0, c0, c1);
        STG_A(sA0, 0, o2);
        BARF(); WAITL0();
        mm16<0, 1>(acc, af, bq1);
        BARF();

        // ph3: Q(1,0) slot0 ; stage (2i+2).B0 -> slot0
        rdA<1>(af, aRd0, c0, c1);
        STG_B(sB0, 0, o2);
        BARF(); WAITL0();
        mm16<1, 0>(acc, af, bq0);
        BARF();

        // ph4: Q(1,1) slot0 ; stage (2i+2).B1 -> slot0 ; counted vmcnt
        STG_B(sB0, 1, o2);
        WAITV6();                 // everything through ph1 landed -> tile 2i+1 ready
        BARF();
        mm16<1, 1>(acc, af, bq1);
        BARF();

        // ph5: Q(0,0) slot1 ; stage (2i+2).A1 -> slot0
        rdA<0>(af, aRd1, c0, c1); rdB<0>(bq0, bRd1, c0, c1);
        STG_A(sA0, 1, o2);
        BARF(); WAITL0();
        mm16<0, 0>(acc, af, bq0);
        BARF();

        // ph6: Q(0,1) slot1 ; stage (2i+3).A0 -> slot1
        rdB<1>(bq1, bRd1, c0, c1);
        STG_A(sA1, 0, o3);
        BARF(); WAITL0();
        mm16<0, 1>(acc, af, bq1);
        BARF();

        // ph7: Q(1,0) slot1 ; stage (2i+3).B0 -> slot1
        rdA<1>(af, aRd1, c0, c1);
        STG_B(sB1, 0, o3);
        BARF(); WAITL0();
        mm16<1, 0>(acc, af, bq0);
        BARF();

        // ph8: Q(1,1) slot1 ; stage (2i+3).B1 -> slot1 ; counted vmcnt
        STG_B(sB1, 1, o3);
        WAITV6();                 // everything through ph5 landed -> tile 2i+2 ready
        BARF();
        mm16<1, 1>(acc, af, bq1);
        BARF();
    }
    asm volatile("s_waitcnt vmcnt(0)" ::: "memory");   // drain tail garbage stages

    // epilogue: row = rowBase + wm*128 + mf*16 + quad*4 + r,
    //           col = colBase + wn*64  + nf*16 + l15
#pragma unroll
    for (int mf = 0; mf < 8; ++mf) {
#pragma unroll
        for (int r = 0; r < 4; ++r) {
            const int row = rowBase + wm * 128 + mf * 16 + quad * 4 + r;
            const size_t base = cEbase + (size_t)row * N + colBase + wn * 64 + l15;
#pragma unroll
            for (int nf = 0; nf < 4; ++nf) {
                float v = acc[mf][nf][r];
                if constexpr (GELU) {
                    ((uint16_t*)Cv)[base + nf * 16] = f2bf(gelu_tanh_f(v));
                } else {
                    ((float*)Cv)[base + nf * 16] = v;
                }
            }
        }
    }
#undef STG_A
#undef STG_B
#undef WAITL0
#undef WAITV6
}

// ---------------------------------------------------------------------------
extern "C" void kernel_launch(void* const* d_in, const int* in_sizes, int n_in,
                              void* d_out, int out_size, void* d_ws, size_t ws_size,
                              hipStream_t stream) {
    const float* x  = (const float*)d_in[0];   // [E,T,H]
    const float* w1 = (const float*)d_in[1];   // [E,H,F]
    const float* w2 = (const float*)d_in[2];   // [E,F,H]
    float* out = (float*)d_out;                // [E,T,H] fp32

    const int E = 8, T = 2048, H = 1024, F = 4096;

    uint16_t* xb  = (uint16_t*)d_ws;                    //  32 MiB
    uint16_t* w1t = xb  + (size_t)E * T * H;            //  64 MiB
    uint16_t* w2t = w1t + (size_t)E * F * H;            //  64 MiB
    uint16_t* h   = w2t + (size_t)E * H * F;            // 128 MiB

    {   // x -> bf16
        int n4 = (E * T * H) / 4;
        cvt_f32_bf16_x4<<<n4 / 256, 256, 0, stream>>>(x, xb, n4);
    }
    // w1 [E][H][F] -> w1t [E][F][H]
    transpose_cvt<<<dim3(F / 64, H / 64, E), 256, 0, stream>>>(w1, w1t, H, F);
    // w2 [E][F][H] -> w2t [E][H][F]
    transpose_cvt<<<dim3(H / 64, F / 64, E), 256, 0, stream>>>(w2, w2t, F, H);

    // GEMM1 + gelu: h[T,F] = gelu(x[T,H] @ w1[H,F]) ; Bt = w1t [F][H]
    gemm_bt_8ph<true ><<<dim3(F / 256, T / 256, E), 512, 0, stream>>>(xb, w1t, h, T, F, H);
    // GEMM2: out[T,H] = h[T,F] @ w2[F,H] ; Bt = w2t [H][F]
    gemm_bt_8ph<false><<<dim3(H / 256, T / 256, E), 512, 0, stream>>>(h, w2t, out, T, H, F);
}

// Round 3
// 620.010 us; speedup vs baseline: 1.0945x; 1.0795x over previous
//
#include <hip/hip_runtime.h>
#include <stdint.h>

// ---------------------------------------------------------------------------
// MLP: out = gelu_tanh(x @ w1) @ w2, per-expert (E=8, T=2048, H=1024, F=4096)
// R6 (= R5 resubmit, hardened): 256x256 8-phase counted-vmcnt schedule with
// inline-asm ds_read_b128 fragment reads (opaque to hipcc's aliasing-driven
// s_waitcnt insertion, which in R4 drained the staging queue every phase and
// serialized the pipeline to 29% MfmaUtil). lgkmcnt(0) + sched_barrier(0)
// per rule #18; "=&v" early-clobber on asm reads. Slab schedule / vmcnt(6)
// at ph4+ph8 only / XOR-chunk LDS swizzle / T1 XCD swizzle / T5 setprio.
// Hazard ledger (verified):
//   - slab overwritten >=1 barrier after last read retires (reads retire at
//     WAITL0 before each phase's closing barrier; the overwriting STG is
//     issued only after that barrier).
//   - slab readiness: WAITV6 leaves exactly the 3 newest half-slabs (6 loads)
//     in flight; everything older has landed; the following barrier makes
//     that true for ALL waves before anyone reads the slab.
// ---------------------------------------------------------------------------

typedef __bf16  bf16x8  __attribute__((ext_vector_type(8)));
typedef float   floatx4 __attribute__((ext_vector_type(4)));
typedef __attribute__((address_space(3))) const uint16_t* lds3p;

__device__ __forceinline__ uint16_t f2bf(float f) {
    uint32_t u = __float_as_uint(f);
    u += 0x7FFF + ((u >> 16) & 1);       // round-to-nearest-even
    return (uint16_t)(u >> 16);
}

__device__ __forceinline__ uint32_t pack2bf(float lo, float hi) {
    return (uint32_t)f2bf(lo) | ((uint32_t)f2bf(hi) << 16);
}

// gelu_tanh(x) == x * sigmoid(2u), u = sqrt(2/pi)*(x + 0.044715 x^3)
__device__ __forceinline__ float gelu_tanh_f(float x) {
    float u2 = 1.5957691216057308f * (x + 0.044715f * x * x * x);
    return x / (1.0f + __expf(-u2));
}

// async global->LDS, 16 bytes per lane; dest = wave-uniform base + lane*16.
__device__ __forceinline__ void async16(const void* g, void* l) {
    __builtin_amdgcn_global_load_lds(
        (__attribute__((address_space(1))) void*)(g),
        (__attribute__((address_space(3))) void*)(l),
        16, 0, 0);
}

#define BARF() do { asm volatile("" ::: "memory");               \
                    __builtin_amdgcn_s_barrier();                \
                    asm volatile("" ::: "memory"); } while (0)

// inline-asm LDS read, compile-time byte offset immediate; early-clobber
// so the dest quad can never alias a later asm's address operand.
template <int OFF>
__device__ __forceinline__ bf16x8 dsr(lds3p p) {
    bf16x8 r;
    asm volatile("ds_read_b128 %0, %1 offset:%2" : "=&v"(r) : "v"(p), "n"(OFF));
    return r;
}

// ---------------------------------------------------------------------------
// fp32 -> bf16 elementwise convert (x), 4 elements/thread
// ---------------------------------------------------------------------------
__global__ void cvt_f32_bf16_x4(const float* __restrict__ in,
                                uint16_t* __restrict__ out, int n4) {
    int i = blockIdx.x * blockDim.x + threadIdx.x;
    if (i >= n4) return;
    float4 v = ((const float4*)in)[i];
    ushort4 o;
    o.x = f2bf(v.x); o.y = f2bf(v.y); o.z = f2bf(v.z); o.w = f2bf(v.w);
    ((ushort4*)out)[i] = o;
}

// ---------------------------------------------------------------------------
// Batched transpose + convert: in [E][R][C] fp32 -> out [E][C][R] bf16.
// ---------------------------------------------------------------------------
__global__ void transpose_cvt(const float* __restrict__ in,
                              uint16_t* __restrict__ out, int R, int C) {
    __shared__ uint32_t lds32[64][33];
    const int e = blockIdx.z;
    in  += (size_t)e * R * C;
    out += (size_t)e * C * R;
    const int c0 = blockIdx.x * 64, r0 = blockIdx.y * 64;
    const int t = threadIdx.x;

    const int g = t >> 4;
    const int col4 = (t & 15) * 4;
    const float* p = in + (size_t)(r0 + 4 * g) * C + c0 + col4;
    float4 v0 = ((const float4*)(p))[0];
    float4 v1 = ((const float4*)(p + C))[0];
    float4 v2 = ((const float4*)(p + 2 * (size_t)C))[0];
    float4 v3 = ((const float4*)(p + 3 * (size_t)C))[0];

    lds32[col4 + 0][2 * g]     = pack2bf(v0.x, v1.x);
    lds32[col4 + 1][2 * g]     = pack2bf(v0.y, v1.y);
    lds32[col4 + 2][2 * g]     = pack2bf(v0.z, v1.z);
    lds32[col4 + 3][2 * g]     = pack2bf(v0.w, v1.w);
    lds32[col4 + 0][2 * g + 1] = pack2bf(v2.x, v3.x);
    lds32[col4 + 1][2 * g + 1] = pack2bf(v2.y, v3.y);
    lds32[col4 + 2][2 * g + 1] = pack2bf(v2.z, v3.z);
    lds32[col4 + 3][2 * g + 1] = pack2bf(v2.w, v3.w);
    __syncthreads();

    const int c = t >> 2, ch = t & 3;
    uint32_t v[8];
#pragma unroll
    for (int k = 0; k < 8; ++k) v[k] = lds32[c][ch * 8 + k];
    uint16_t* op = out + (size_t)(c0 + c) * R + r0 + ch * 16;
    *(uint4*)(op)     = make_uint4(v[0], v[1], v[2], v[3]);
    *(uint4*)(op + 8) = make_uint4(v[4], v[5], v[6], v[7]);
}

// ---------------------------------------------------------------------------
// 8-phase 256x256 GEMM helpers — asm ds_read fragment loads
// p0/p1: per-wave base pointers for k-sub 0/1 (lane offset + XOR chunk baked
// in); compile-time offset walks QM/QN slab (16 KiB) and 16-row sub-tiles.
// ---------------------------------------------------------------------------
template <int QM>
__device__ __forceinline__ void rdA(bf16x8 (&af)[4][2], lds3p p0, lds3p p1) {
    af[0][0] = dsr<QM * 16384 +    0>(p0);  af[0][1] = dsr<QM * 16384 +    0>(p1);
    af[1][0] = dsr<QM * 16384 + 2048>(p0);  af[1][1] = dsr<QM * 16384 + 2048>(p1);
    af[2][0] = dsr<QM * 16384 + 4096>(p0);  af[2][1] = dsr<QM * 16384 + 4096>(p1);
    af[3][0] = dsr<QM * 16384 + 6144>(p0);  af[3][1] = dsr<QM * 16384 + 6144>(p1);
}

template <int QN>
__device__ __forceinline__ void rdB(bf16x8 (&b)[2][2], lds3p p0, lds3p p1) {
    b[0][0] = dsr<QN * 16384 +    0>(p0);   b[0][1] = dsr<QN * 16384 +    0>(p1);
    b[1][0] = dsr<QN * 16384 + 2048>(p0);   b[1][1] = dsr<QN * 16384 + 2048>(p1);
}

template <int QM, int QN>
__device__ __forceinline__ void mm16(floatx4 (&acc)[8][4],
                                     const bf16x8 (&af)[4][2],
                                     const bf16x8 (&b)[2][2]) {
    __builtin_amdgcn_s_setprio(1);
#pragma unroll
    for (int m = 0; m < 4; ++m)
#pragma unroll
        for (int n = 0; n < 2; ++n) {
            floatx4 c = acc[QM * 4 + m][QN * 2 + n];
            c = __builtin_amdgcn_mfma_f32_16x16x32_bf16(af[m][0], b[n][0], c, 0, 0, 0);
            c = __builtin_amdgcn_mfma_f32_16x16x32_bf16(af[m][1], b[n][1], c, 0, 0, 0);
            acc[QM * 4 + m][QN * 2 + n] = c;
        }
    __builtin_amdgcn_s_setprio(0);
}

// ---------------------------------------------------------------------------
// GEMM: C[M][N] = A[M][K] @ Bt[N][K]^T, bf16 in, fp32 accum.
// 256x256 tile, BK=64, 512 threads = 8 waves (2Mx4N), 128x64 per wave.
// LDS slot: [256][64] elems, physical chunk pc = kc ^ (row&7) (XOR swizzle;
// source-side global address permutation keeps global_load_lds dest linear).
// vmcnt(6) only at ph4/ph8; a slab is staged >=1 barrier after its last read.
// ---------------------------------------------------------------------------
template <bool GELU>
__global__ __launch_bounds__(512, 2)
void gemm_bt_8ph(const uint16_t* __restrict__ A,
                 const uint16_t* __restrict__ Bt,
                 void* __restrict__ Cv, int M, int N, int K) {
    __shared__ __attribute__((aligned(16))) uint16_t lds_a[2][256 * 64];
    __shared__ __attribute__((aligned(16))) uint16_t lds_b[2][256 * 64];

    // T1: bijective XCD-chunked swizzle on the flattened 3D grid
    const int nx = gridDim.x, ny = gridDim.y;
    int flat = blockIdx.x + nx * (blockIdx.y + ny * blockIdx.z);
    const int nwg = nx * ny * (int)gridDim.z;      // multiple of 8 by launch
    flat = (flat & 7) * (nwg >> 3) + (flat >> 3);
    const int bx  = flat % nx;
    const int tmp = flat / nx;
    const int by  = tmp % ny;
    const int e   = tmp / ny;

    A  += (size_t)e * M * K;
    Bt += (size_t)e * N * K;
    const size_t cEbase = (size_t)e * M * N;
    const int rowBase = by * 256, colBase = bx * 256;

    const int tid  = threadIdx.x;
    const int lane = tid & 63, wave = tid >> 6;
    const int wm = wave >> 2, wn = wave & 3;
    const int quad = lane >> 4, l15 = lane & 15, lx = l15 & 7;
    const int c0 = (quad ^ lx) * 8;          // k-chunk offsets (elems), ksub 0
    const int c1 = ((4 + quad) ^ lx) * 8;    // ksub 1

    const size_t K32  = (size_t)32 * K;
    const size_t K64  = (size_t)64 * K;
    const size_t K128 = (size_t)128 * K;

    // staging: thread t covers physical sub-row (t>>3), chunk (t&7);
    // stored logical chunk kc = (t&7) ^ ((t>>3)&7)  -> fold into global addr.
    const int sxor = ((tid & 7) ^ ((tid >> 3) & 7)) * 8;
    const uint16_t* gA = A  + (size_t)(rowBase + (tid >> 3)) * K + sxor;
    const uint16_t* gB = Bt + (size_t)(colBase + (tid >> 8) * 64 +
                                       ((tid >> 3) & 31)) * K + sxor;

    uint16_t* sA0 = lds_a[0] + tid * 8;
    uint16_t* sA1 = lds_a[1] + tid * 8;
    uint16_t* sB0 = lds_b[0] + tid * 8;
    uint16_t* sB1 = lds_b[1] + tid * 8;

    // per-wave fragment base pointers (slot x ksub), XOR chunk baked in
    lds3p aP0c0 = (lds3p)(lds_a[0] + wm * 4096 + l15 * 64 + c0);
    lds3p aP0c1 = (lds3p)(lds_a[0] + wm * 4096 + l15 * 64 + c1);
    lds3p aP1c0 = (lds3p)(lds_a[1] + wm * 4096 + l15 * 64 + c0);
    lds3p aP1c1 = (lds3p)(lds_a[1] + wm * 4096 + l15 * 64 + c1);
    lds3p bP0c0 = (lds3p)(lds_b[0] + wn * 2048 + l15 * 64 + c0);
    lds3p bP0c1 = (lds3p)(lds_b[0] + wn * 2048 + l15 * 64 + c1);
    lds3p bP1c0 = (lds3p)(lds_b[1] + wn * 2048 + l15 * 64 + c0);
    lds3p bP1c1 = (lds3p)(lds_b[1] + wn * 2048 + l15 * 64 + c1);

#define STG_A(dst, qmv, koff) do {                                   \
        const uint16_t* g_ = gA + (qmv) * K64 + (koff);              \
        async16(g_,        (dst) + (qmv) * 8192);                    \
        async16(g_ + K128, (dst) + (qmv) * 8192 + 4096); } while (0)
#define STG_B(dst, qnv, koff) do {                                   \
        const uint16_t* g_ = gB + (qnv) * K32 + (koff);              \
        async16(g_,        (dst) + (qnv) * 8192);                    \
        async16(g_ + K128, (dst) + (qnv) * 8192 + 4096); } while (0)
#define WAITL0() do { asm volatile("s_waitcnt lgkmcnt(0)" ::: "memory"); \
                      __builtin_amdgcn_sched_barrier(0); } while (0)
#define WAITV6() asm volatile("s_waitcnt vmcnt(6)"  ::: "memory")

    floatx4 acc[8][4] = {};
    bf16x8 af[4][2], bq0[2][2], bq1[2][2];

    const int KT = K >> 6;        // K-tiles of 64
    const int NI = KT >> 1;       // iterations (2 K-tiles each)

    // prologue: tile0 {A0,B0,B1,A1} -> slot0 ; tile1 {A0,B0,B1} -> slot1
    STG_A(sA0, 0, 0); STG_B(sB0, 0, 0); STG_B(sB0, 1, 0); STG_A(sA0, 1, 0);
    STG_A(sA1, 0, 64); STG_B(sB1, 0, 64); STG_B(sB1, 1, 64);
    WAITV6();                     // tile0's 8 loads landed; tile1's 6 in flight
    BARF();

#pragma unroll 1
    for (int i = 0; i < NI; ++i) {
        const size_t oB = (size_t)(2 * i + 1) * 64;              // tile 2i+1
        const int t2 = (2 * i + 2 < KT) ? (2 * i + 2) : 0;       // wrap: dead-slab garbage
        const size_t o2 = (size_t)t2 * 64;
        const size_t o3 = o2 + 64;

        // ph1: Q(0,0) slot0 ; stage (2i+1).A1 -> slot1
        rdA<0>(af, aP0c0, aP0c1); rdB<0>(bq0, bP0c0, bP0c1);
        STG_A(sA1, 1, oB);
        BARF(); WAITL0();
        mm16<0, 0>(acc, af, bq0);
        BARF();

        // ph2: Q(0,1) slot0 ; stage (2i+2).A0 -> slot0
        rdB<1>(bq1, bP0c0, bP0c1);
        STG_A(sA0, 0, o2);
        BARF(); WAITL0();
        mm16<0, 1>(acc, af, bq1);
        BARF();

        // ph3: Q(1,0) slot0 ; stage (2i+2).B0 -> slot0
        rdA<1>(af, aP0c0, aP0c1);
        STG_B(sB0, 0, o2);
        BARF(); WAITL0();
        mm16<1, 0>(acc, af, bq0);
        BARF();

        // ph4: Q(1,1) slot0 ; stage (2i+2).B1 -> slot0 ; counted vmcnt
        STG_B(sB0, 1, o2);
        WAITV6();                 // everything through ph1 landed -> tile 2i+1 ready
        BARF();
        mm16<1, 1>(acc, af, bq1);
        BARF();

        // ph5: Q(0,0) slot1 ; stage (2i+2).A1 -> slot0
        rdA<0>(af, aP1c0, aP1c1); rdB<0>(bq0, bP1c0, bP1c1);
        STG_A(sA0, 1, o2);
        BARF(); WAITL0();
        mm16<0, 0>(acc, af, bq0);
        BARF();

        // ph6: Q(0,1) slot1 ; stage (2i+3).A0 -> slot1
        rdB<1>(bq1, bP1c0, bP1c1);
        STG_A(sA1, 0, o3);
        BARF(); WAITL0();
        mm16<0, 1>(acc, af, bq1);
        BARF();

        // ph7: Q(1,0) slot1 ; stage (2i+3).B0 -> slot1
        rdA<1>(af, aP1c0, aP1c1);
        STG_B(sB1, 0, o3);
        BARF(); WAITL0();
        mm16<1, 0>(acc, af, bq0);
        BARF();

        // ph8: Q(1,1) slot1 ; stage (2i+3).B1 -> slot1 ; counted vmcnt
        STG_B(sB1, 1, o3);
        WAITV6();                 // everything through ph5 landed -> tile 2i+2 ready
        BARF();
        mm16<1, 1>(acc, af, bq1);
        BARF();
    }
    asm volatile("s_waitcnt vmcnt(0)" ::: "memory");   // drain tail garbage stages

    // epilogue: row = rowBase + wm*128 + mf*16 + quad*4 + r,
    //           col = colBase + wn*64  + nf*16 + l15
#pragma unroll
    for (int mf = 0; mf < 8; ++mf) {
#pragma unroll
        for (int r = 0; r < 4; ++r) {
            const int row = rowBase + wm * 128 + mf * 16 + quad * 4 + r;
            const size_t base = cEbase + (size_t)row * N + colBase + wn * 64 + l15;
#pragma unroll
            for (int nf = 0; nf < 4; ++nf) {
                float v = acc[mf][nf][r];
                if constexpr (GELU) {
                    ((uint16_t*)Cv)[base + nf * 16] = f2bf(gelu_tanh_f(v));
                } else {
                    ((float*)Cv)[base + nf * 16] = v;
                }
            }
        }
    }
#undef STG_A
#undef STG_B
#undef WAITL0
#undef WAITV6
}

// ---------------------------------------------------------------------------
extern "C" void kernel_launch(void* const* d_in, const int* in_sizes, int n_in,
                              void* d_out, int out_size, void* d_ws, size_t ws_size,
                              hipStream_t stream) {
    const float* x  = (const float*)d_in[0];   // [E,T,H]
    const float* w1 = (const float*)d_in[1];   // [E,H,F]
    const float* w2 = (const float*)d_in[2];   // [E,F,H]
    float* out = (float*)d_out;                // [E,T,H] fp32

    const int E = 8, T = 2048, H = 1024, F = 4096;

    uint16_t* xb  = (uint16_t*)d_ws;                    //  32 MiB
    uint16_t* w1t = xb  + (size_t)E * T * H;            //  64 MiB
    uint16_t* w2t = w1t + (size_t)E * F * H;            //  64 MiB
    uint16_t* h   = w2t + (size_t)E * H * F;            // 128 MiB

    {   // x -> bf16
        int n4 = (E * T * H) / 4;
        cvt_f32_bf16_x4<<<n4 / 256, 256, 0, stream>>>(x, xb, n4);
    }
    // w1 [E][H][F] -> w1t [E][F][H]
    transpose_cvt<<<dim3(F / 64, H / 64, E), 256, 0, stream>>>(w1, w1t, H, F);
    // w2 [E][F][H] -> w2t [E][H][F]
    transpose_cvt<<<dim3(H / 64, F / 64, E), 256, 0, stream>>>(w2, w2t, F, H);

    // GEMM1 + gelu: h[T,F] = gelu(x[T,H] @ w1[H,F]) ; Bt = w1t [F][H]
    gemm_bt_8ph<true ><<<dim3(F / 256, T / 256, E), 512, 0, stream>>>(xb, w1t, h, T, F, H);
    // GEMM2: out[T,H] = h[T,F] @ w2[F,H] ; Bt = w2t [H][F]
    gemm_bt_8ph<false><<<dim3(H / 256, T / 256, E), 512, 0, stream>>>(h, w2t, out, T, H, F);
}